// Round 7
// baseline (543.527 us; speedup 1.0000x reference)
//
#include <hip/hip_runtime.h>
#include <hip/hip_bf16.h>

#define BB 16
#define NXX 1024
#define NYY 1024
#define DINX 768
#define DINY 283
#define NHH 8
#define HKK 10
#define DKV 80
#define NORMF 0.31622776601683794f  // 1/sqrt(10)

#define NP 1310720UL   // floats per [bh][*] plane (16*8*1024*10)
#define NR2 4194304UL  // floats in KVr (131072 rows * 32)

// ws float layout:
//   Pq[4][NP]    Q partials, head-major ((b*8+h)*1024+n)*10+d
//   PKd[2][NP]   K partials, dim-pair-major ((bh*5+dp)*2048 + n*2 + par), pre-scaled by NORMF
//   PKr[2][NR2]  K+V partials, padded row-major: row=(bh*1024+n), 32 f32/row: [0..9]=K~ [16..25]=V
//   Qhm[NP], Kdm[NP], KVr[NR2]  reduced finals
// total (8*NP + 3*NR2)*4 B = 92 MB

__device__ __forceinline__ float dot10(const float* a, const float* b) {
  float s = a[0] * b[0];
#pragma unroll
  for (int d = 1; d < 10; ++d) s = fmaf(a[d], b[d], s);
  return s;
}

// ---------------- Q projection: 1024 blocks (256 rowtiles x 4 ksplits), 256 thr ----------------
__global__ __launch_bounds__(256) void proj_q(
    const float* __restrict__ X, const float* __restrict__ Wq, float* __restrict__ Pq) {
  __shared__ float Xs[64 * 33];
  const int t = threadIdx.x;
  const int rt = blockIdx.x >> 2;
  const int ks = blockIdx.x & 3;
  const int w = __builtin_amdgcn_readfirstlane(t >> 6);
  const int lane = t & 63;
  const int cbase = w * 20;
  const int kbase = ks * 192;

  float acc[20];
#pragma unroll
  for (int c = 0; c < 20; ++c) acc[c] = 0.f;

#pragma unroll 1
  for (int ch = 0; ch < 6; ++ch) {
    const int dk = kbase + ch * 32;
    __syncthreads();
    for (int u = t; u < 2048; u += 256) {
      const int r = u >> 5, c = u & 31;
      Xs[r * 33 + c] = X[(size_t)(rt * 64 + r) * DINX + dk + c];
    }
    __syncthreads();
    float xv[32];
#pragma unroll
    for (int k = 0; k < 32; ++k) xv[k] = Xs[lane * 33 + k];
#pragma unroll
    for (int c = 0; c < 20; ++c) {
      const float* wr = Wq + (size_t)(cbase + c) * DINX + dk;  // wave-uniform -> s_load
#pragma unroll
      for (int k = 0; k < 32; ++k) acc[c] = fmaf(wr[k], xv[k], acc[c]);
    }
  }

  const int row = rt * 64 + lane;
  const int b = row >> 10, n = row & 1023;
  float* dst = Pq + (size_t)ks * NP;
#pragma unroll
  for (int c = 0; c < 20; ++c) {
    const int cc = cbase + c, h = cc / 10, d = cc - 10 * h;
    dst[(((size_t)b * NHH + h) * 1024 + n) * 10 + d] = acc[c];
  }
}

// ---------------- K/V projection: 512 blocks (256 rowtiles x 2 ksplits), 512 thr ----------------
// waves 0-3 -> K cols, waves 4-7 -> V cols; shared Y tile.
// K partials written pre-scaled to BOTH PKd (dim-pair-major) and PKr (padded row-major);
// V partials to PKr only.
__global__ __launch_bounds__(512) void proj_kv(
    const float* __restrict__ Y, const float* __restrict__ WK, const float* __restrict__ WV,
    float* __restrict__ PKd, float* __restrict__ PKr) {
  __shared__ float Xs[64 * 33];
  const int t = threadIdx.x;
  const int rt = blockIdx.x >> 1;
  const int ks = blockIdx.x & 1;
  const int w = __builtin_amdgcn_readfirstlane(t >> 6);
  const int lane = t & 63;
  const bool isV = (w >= 4);
  const int cbase = (isV ? (w - 4) : w) * 20;
  const float* W = isV ? WV : WK;
  const int kbase = ks * 160;
  const int nch = ks ? 4 : 5;

  float acc[20];
#pragma unroll
  for (int c = 0; c < 20; ++c) acc[c] = 0.f;

#pragma unroll 1
  for (int ch = 0; ch < nch; ++ch) {
    const int dk = kbase + ch * 32;
    __syncthreads();
    for (int u = t; u < 2048; u += 512) {
      const int r = u >> 5, c = u & 31;
      const int d = dk + c;
      Xs[r * 33 + c] = (d < DINY) ? Y[(size_t)(rt * 64 + r) * DINY + d] : 0.f;
    }
    __syncthreads();
    float xv[32];
#pragma unroll
    for (int k = 0; k < 32; ++k) xv[k] = Xs[lane * 33 + k];
    if (dk + 32 <= DINY) {
#pragma unroll
      for (int c = 0; c < 20; ++c) {
        const float* wr = W + (size_t)(cbase + c) * DINY + dk;
#pragma unroll
        for (int k = 0; k < 32; ++k) acc[c] = fmaf(wr[k], xv[k], acc[c]);
      }
    } else {  // tail: 27 valid dims
#pragma unroll
      for (int c = 0; c < 20; ++c) {
        const float* wr = W + (size_t)(cbase + c) * DINY + dk;
#pragma unroll
        for (int k = 0; k < 27; ++k) acc[c] = fmaf(wr[k], xv[k], acc[c]);
      }
    }
  }

  const int row = rt * 64 + lane;
  const int b = row >> 10, n = row & 1023;
#pragma unroll
  for (int c = 0; c < 20; ++c) {
    const int cc = cbase + c, h = cc / 10, d = cc - 10 * h;
    const size_t bh = (size_t)b * NHH + h;
    const size_t grow = bh * 1024 + n;
    if (!isV) {
      const float v = acc[c] * NORMF;
      PKd[(size_t)ks * NP + (bh * 5 + (d >> 1)) * 2048 + n * 2 + (d & 1)] = v;
      PKr[(size_t)ks * NR2 + grow * 32 + d] = v;
    } else {
      PKr[(size_t)ks * NR2 + grow * 32 + 16 + d] = acc[c];
    }
  }
}

// ---------------- reduce partials -> finals (F = [Qhm NP][Kdm NP][KVr NR2]) ----------------
__global__ __launch_bounds__(256) void reduce_k(const float* __restrict__ ws, float* __restrict__ F) {
  const int NIQ = NP / 4;          // 327680 f4
  const int NIK = NP / 4;          // 327680 f4
  const int NIR = NR2 / 4;         // 1048576 f4
  const float4* w4 = (const float4*)ws;
  float4* F4 = (float4*)F;
  const int total = NIQ + NIK + NIR;
  for (int i = blockIdx.x * 256 + threadIdx.x; i < total; i += gridDim.x * 256) {
    float4 s;
    if (i < NIQ) {
      const float4* P = w4;  // 4 planes of NIQ
      float4 a = P[i], b = P[i + NIQ], c = P[i + 2 * NIQ], d = P[i + 3 * NIQ];
      s.x = a.x + b.x + c.x + d.x; s.y = a.y + b.y + c.y + d.y;
      s.z = a.z + b.z + c.z + d.z; s.w = a.w + b.w + c.w + d.w;
      F4[i] = s;
    } else if (i < NIQ + NIK) {
      const int j = i - NIQ;
      const float4* P = w4 + 4 * NIQ;  // 2 planes of NIK
      float4 a = P[j], b = P[j + NIK];
      s.x = a.x + b.x; s.y = a.y + b.y; s.z = a.z + b.z; s.w = a.w + b.w;
      F4[i] = s;
    } else {
      const int j = i - NIQ - NIK;
      const float4* P = w4 + 6 * NIQ;  // 2 planes of NIR
      float4 a = P[j], b = P[j + NIR];
      s.x = a.x + b.x; s.y = a.y + b.y; s.z = a.z + b.z; s.w = a.w + b.w;
      F4[i] = s;
    }
  }
}

// ---------------- fused attention: 2048 blocks x 64 thr (1 wave = 64 q-rows of one (b,h)) ----
// Pass 1: thread=q-row; K/V via wave-uniform loads of 128B/k records (s_load/broadcast);
//         thread-local l and PV accumulation -> NO cross-lane reduction, no LDS, no VMEM scatter.
// Pass 2: lane=2 k-cols; q' inner loop reads q-rows + rl via LDS broadcast; recomputes
//         p with a bit-identical fmaf chain; coalesced float2 dist stores. Exact fp32 output.
__global__ __launch_bounds__(64) void attn_kernel(
    const float* __restrict__ Qhm, const float* __restrict__ Kdm,
    const float* __restrict__ KVr, float* __restrict__ out_att,
    float* __restrict__ out_dist) {
  __shared__ float qs[64 * 12];  // per q-row: q[0..9], rl, pad

  const int lane = threadIdx.x;
  const int bid = blockIdx.x;
  const int nt = bid & 15;       // n-tile fast -> 16 consecutive blocks share (b,h) K/V stream
  const int bh = bid >> 4;
  const int n = nt * 64 + lane;

  // pass 1 -------------------------------------------------------------
  float qr[10];
  {
    const float2* qp = (const float2*)(Qhm + ((size_t)bh * 1024 + n) * 10);
#pragma unroll
    for (int dd = 0; dd < 5; ++dd) {
      float2 v = qp[dd];
      qr[2 * dd] = v.x; qr[2 * dd + 1] = v.y;
    }
  }

  float acc[10];
#pragma unroll
  for (int d = 0; d < 10; ++d) acc[d] = 0.f;
  float l = 0.f;

  const float4* kv4 = (const float4*)(KVr + (size_t)bh * 1024 * 32);
#pragma unroll 2
  for (int k = 0; k < 1024; ++k) {
    const float4* rec = kv4 + (size_t)k * 8;
    float4 a0 = rec[0], a1 = rec[1], a2 = rec[2];
    float kf[10] = {a0.x, a0.y, a0.z, a0.w, a1.x, a1.y, a1.z, a1.w, a2.x, a2.y};
    const float p = __expf(dot10(qr, kf));
    l += p;
    float4 b0 = rec[4], b1 = rec[5], b2 = rec[6];
    float vf[10] = {b0.x, b0.y, b0.z, b0.w, b1.x, b1.y, b1.z, b1.w, b2.x, b2.y};
#pragma unroll
    for (int d = 0; d < 10; ++d) acc[d] = fmaf(p, vf[d], acc[d]);
  }

  const float rl = 1.0f / l;
  {
    float* ap = out_att + ((size_t)(bh >> 3) * 1024 + n) * DKV + (bh & 7) * HKK;
#pragma unroll
    for (int dd = 0; dd < 5; ++dd)
      *(float2*)&ap[2 * dd] = make_float2(acc[2 * dd] * rl, acc[2 * dd + 1] * rl);
  }
#pragma unroll
  for (int d = 0; d < 10; ++d) qs[lane * 12 + d] = qr[d];
  qs[lane * 12 + 10] = rl;
  __syncthreads();

  // pass 2 -------------------------------------------------------------
  const float4* kp4 = (const float4*)(Kdm + (size_t)bh * 10240);
  float* drow = out_dist + ((size_t)bh * 1024 + (size_t)nt * 64) * 1024;
#pragma unroll 1
  for (int c = 0; c < 8; ++c) {
    const int kb = c * 128 + lane * 2;
    float kA[10], kB[10];
#pragma unroll
    for (int dp = 0; dp < 5; ++dp) {
      float4 v = kp4[dp * 512 + (kb >> 1)];  // {K[2dp][kb],K[2dp+1][kb],K[2dp][kb+1],K[2dp+1][kb+1]}
      kA[2 * dp] = v.x; kA[2 * dp + 1] = v.y;
      kB[2 * dp] = v.z; kB[2 * dp + 1] = v.w;
    }
#pragma unroll 4
    for (int qq = 0; qq < 64; ++qq) {
      float4 qa = *(const float4*)&qs[qq * 12];
      float4 qb = *(const float4*)&qs[qq * 12 + 4];
      float4 qc = *(const float4*)&qs[qq * 12 + 8];  // {q8, q9, rl, pad}
      float qv[10] = {qa.x, qa.y, qa.z, qa.w, qb.x, qb.y, qb.z, qb.w, qc.x, qc.y};
      const float rlq = qc.z;
      const float p0 = __expf(dot10(qv, kA)) * rlq;
      const float p1 = __expf(dot10(qv, kB)) * rlq;
      *(float2*)&drow[(size_t)qq * 1024 + kb] = make_float2(p0, p1);
    }
  }
}

extern "C" void kernel_launch(void* const* d_in, const int* in_sizes, int n_in,
                              void* d_out, int out_size, void* d_ws, size_t ws_size,
                              hipStream_t stream) {
  (void)in_sizes; (void)n_in; (void)out_size; (void)ws_size;
  const float* x = (const float*)d_in[0];
  const float* y = (const float*)d_in[1];
  // d_in[2] = attn_mask (dead arg in the reference forward)
  const float* Wq = (const float*)d_in[3];
  const float* Wk = (const float*)d_in[4];
  const float* Wv = (const float*)d_in[5];

  float* out = (float*)d_out;
  float* att_out = out;
  float* dist_out = out + (size_t)BB * NXX * DKV;

  float* ws = (float*)d_ws;
  float* Pq  = ws;                         // 4 * NP
  float* PKd = ws + 4 * NP;                // 2 * NP
  float* PKr = ws + 6 * NP;                // 2 * NR2
  float* F   = ws + 8 * NP + 2 * NR2;      // [Qhm NP][Kdm NP][KVr NR2]
  float* Qhm = F;
  float* Kdm = F + NP;
  float* KVr = F + 2 * NP;

  proj_q<<<1024, 256, 0, stream>>>(x, Wq, Pq);
  proj_kv<<<512, 512, 0, stream>>>(y, Wk, Wv, PKd, PKr);
  reduce_k<<<2048, 256, 0, stream>>>(ws, F);
  attn_kernel<<<BB * NHH * 16, 64, 0, stream>>>(Qhm, Kdm, KVr, att_out, dist_out);
}

// Round 8
// 484.853 us; speedup vs baseline: 1.1210x; 1.1210x over previous
//
#include <hip/hip_runtime.h>
#include <hip/hip_bf16.h>

#define BB 16
#define NXX 1024
#define NYY 1024
#define DINX 768
#define DINY 283
#define NHH 8
#define HKK 10
#define DKV 80
#define NORMF 0.31622776601683794f  // 1/sqrt(10)

#define NP 1310720UL   // floats per [bh][*] plane (16*8*1024*10)
#define NR2 4194304UL  // floats in KVr (131072 rows * 32)

// ws float layout:
//   Pq[4][NP]    Q partials, head-major ((b*8+h)*1024+n)*10+d
//   PKd[2][NP]   K partials, dim-pair-major ((bh*5+dp)*2048 + n*2 + par), pre-scaled by NORMF
//   PKr[2][NR2]  K+V partials, padded row-major: row=(bh*1024+n), 32 f32: [0..9]=K~ [16..25]=V
//   Qhm[NP], Kdm[NP], KVr[NR2]  reduced finals
//   qrl[131072*12]  per q-row: {q[0..9], rl, pad}  (written by attn_lv, read by attn_dist)
// total (8*NP + 3*NR2 + 1.57M)*4 B = 98.6 MB

__device__ __forceinline__ float dot10(const float* a, const float* b) {
  float s = a[0] * b[0];
#pragma unroll
  for (int d = 1; d < 10; ++d) s = fmaf(a[d], b[d], s);
  return s;
}

// ---------------- Q projection: 1024 blocks (256 rowtiles x 4 ksplits), 256 thr ----------------
__global__ __launch_bounds__(256) void proj_q(
    const float* __restrict__ X, const float* __restrict__ Wq, float* __restrict__ Pq) {
  __shared__ float Xs[64 * 33];
  const int t = threadIdx.x;
  const int rt = blockIdx.x >> 2;
  const int ks = blockIdx.x & 3;
  const int w = __builtin_amdgcn_readfirstlane(t >> 6);
  const int lane = t & 63;
  const int cbase = w * 20;
  const int kbase = ks * 192;

  float acc[20];
#pragma unroll
  for (int c = 0; c < 20; ++c) acc[c] = 0.f;

#pragma unroll 1
  for (int ch = 0; ch < 6; ++ch) {
    const int dk = kbase + ch * 32;
    __syncthreads();
    for (int u = t; u < 2048; u += 256) {
      const int r = u >> 5, c = u & 31;
      Xs[r * 33 + c] = X[(size_t)(rt * 64 + r) * DINX + dk + c];
    }
    __syncthreads();
    float xv[32];
#pragma unroll
    for (int k = 0; k < 32; ++k) xv[k] = Xs[lane * 33 + k];
#pragma unroll
    for (int c = 0; c < 20; ++c) {
      const float* wr = Wq + (size_t)(cbase + c) * DINX + dk;  // wave-uniform -> s_load
#pragma unroll
      for (int k = 0; k < 32; ++k) acc[c] = fmaf(wr[k], xv[k], acc[c]);
    }
  }

  const int row = rt * 64 + lane;
  const int b = row >> 10, n = row & 1023;
  float* dst = Pq + (size_t)ks * NP;
#pragma unroll
  for (int c = 0; c < 20; ++c) {
    const int cc = cbase + c, h = cc / 10, d = cc - 10 * h;
    dst[(((size_t)b * NHH + h) * 1024 + n) * 10 + d] = acc[c];
  }
}

// ---------------- K/V projection: 512 blocks (256 rowtiles x 2 ksplits), 512 thr ----------------
__global__ __launch_bounds__(512) void proj_kv(
    const float* __restrict__ Y, const float* __restrict__ WK, const float* __restrict__ WV,
    float* __restrict__ PKd, float* __restrict__ PKr) {
  __shared__ float Xs[64 * 33];
  const int t = threadIdx.x;
  const int rt = blockIdx.x >> 1;
  const int ks = blockIdx.x & 1;
  const int w = __builtin_amdgcn_readfirstlane(t >> 6);
  const int lane = t & 63;
  const bool isV = (w >= 4);
  const int cbase = (isV ? (w - 4) : w) * 20;
  const float* W = isV ? WV : WK;
  const int kbase = ks * 160;
  const int nch = ks ? 4 : 5;

  float acc[20];
#pragma unroll
  for (int c = 0; c < 20; ++c) acc[c] = 0.f;

#pragma unroll 1
  for (int ch = 0; ch < nch; ++ch) {
    const int dk = kbase + ch * 32;
    __syncthreads();
    for (int u = t; u < 2048; u += 512) {
      const int r = u >> 5, c = u & 31;
      const int d = dk + c;
      Xs[r * 33 + c] = (d < DINY) ? Y[(size_t)(rt * 64 + r) * DINY + d] : 0.f;
    }
    __syncthreads();
    float xv[32];
#pragma unroll
    for (int k = 0; k < 32; ++k) xv[k] = Xs[lane * 33 + k];
    if (dk + 32 <= DINY) {
#pragma unroll
      for (int c = 0; c < 20; ++c) {
        const float* wr = W + (size_t)(cbase + c) * DINY + dk;
#pragma unroll
        for (int k = 0; k < 32; ++k) acc[c] = fmaf(wr[k], xv[k], acc[c]);
      }
    } else {  // tail: 27 valid dims
#pragma unroll
      for (int c = 0; c < 20; ++c) {
        const float* wr = W + (size_t)(cbase + c) * DINY + dk;
#pragma unroll
        for (int k = 0; k < 27; ++k) acc[c] = fmaf(wr[k], xv[k], acc[c]);
      }
    }
  }

  const int row = rt * 64 + lane;
  const int b = row >> 10, n = row & 1023;
#pragma unroll
  for (int c = 0; c < 20; ++c) {
    const int cc = cbase + c, h = cc / 10, d = cc - 10 * h;
    const size_t bh = (size_t)b * NHH + h;
    const size_t grow = bh * 1024 + n;
    if (!isV) {
      const float v = acc[c] * NORMF;
      PKd[(size_t)ks * NP + (bh * 5 + (d >> 1)) * 2048 + n * 2 + (d & 1)] = v;
      PKr[(size_t)ks * NR2 + grow * 32 + d] = v;
    } else {
      PKr[(size_t)ks * NR2 + grow * 32 + 16 + d] = acc[c];
    }
  }
}

// ---------------- reduce partials -> finals (F = [Qhm NP][Kdm NP][KVr NR2]) ----------------
__global__ __launch_bounds__(256) void reduce_k(const float* __restrict__ ws, float* __restrict__ F) {
  const int NIQ = NP / 4;
  const int NIK = NP / 4;
  const int NIR = NR2 / 4;
  const float4* w4 = (const float4*)ws;
  float4* F4 = (float4*)F;
  const int total = NIQ + NIK + NIR;
  for (int i = blockIdx.x * 256 + threadIdx.x; i < total; i += gridDim.x * 256) {
    float4 s;
    if (i < NIQ) {
      const float4* P = w4;
      float4 a = P[i], b = P[i + NIQ], c = P[i + 2 * NIQ], d = P[i + 3 * NIQ];
      s.x = a.x + b.x + c.x + d.x; s.y = a.y + b.y + c.y + d.y;
      s.z = a.z + b.z + c.z + d.z; s.w = a.w + b.w + c.w + d.w;
      F4[i] = s;
    } else if (i < NIQ + NIK) {
      const int j = i - NIQ;
      const float4* P = w4 + 4 * NIQ;
      float4 a = P[j], b = P[j + NIK];
      s.x = a.x + b.x; s.y = a.y + b.y; s.z = a.z + b.z; s.w = a.w + b.w;
      F4[i] = s;
    } else {
      const int j = i - NIQ - NIK;
      const float4* P = w4 + 6 * NIQ;
      float4 a = P[j], b = P[j + NIR];
      s.x = a.x + b.x; s.y = a.y + b.y; s.z = a.z + b.z; s.w = a.w + b.w;
      F4[i] = s;
    }
  }
}

// ---------------- attn A: l + att. 2048 blocks x 256 thr ----------------
// block = (bh, 64-q-row tile); 4 waves k-split 256 k each (s_load record stream = 32 KB/wave);
// lane = q-row; thread-local l/PV; cross-wave combine via LDS; writes att + qrl records.
__global__ __launch_bounds__(256) void attn_lv(
    const float* __restrict__ Qhm, const float* __restrict__ KVr,
    float* __restrict__ out_att, float* __restrict__ qrl) {
  __shared__ float pl[4][64];
  __shared__ float pa[4][64][10];

  const int t = threadIdx.x;
  const int w = __builtin_amdgcn_readfirstlane(t >> 6);
  const int lane = t & 63;
  const int bid = blockIdx.x;
  const int qt = bid & 15;
  const int bh = bid >> 4;
  const int n = qt * 64 + lane;

  float qr[10];
  {
    const float2* qp = (const float2*)(Qhm + ((size_t)bh * 1024 + n) * 10);
#pragma unroll
    for (int dd = 0; dd < 5; ++dd) {
      float2 v = qp[dd];
      qr[2 * dd] = v.x; qr[2 * dd + 1] = v.y;
    }
  }

  float acc[10];
#pragma unroll
  for (int d = 0; d < 10; ++d) acc[d] = 0.f;
  float l = 0.f;

  const float4* kv4 = (const float4*)(KVr + (size_t)bh * 32768) + (size_t)w * 256 * 8;
#pragma unroll 2
  for (int k = 0; k < 256; ++k) {
    const float4* rec = kv4 + (size_t)k * 8;
    float4 a0 = rec[0], a1 = rec[1], a2 = rec[2];
    float kf[10] = {a0.x, a0.y, a0.z, a0.w, a1.x, a1.y, a1.z, a1.w, a2.x, a2.y};
    const float p = __expf(dot10(qr, kf));
    l += p;
    float4 b0 = rec[4], b1 = rec[5], b2 = rec[6];
    float vf[10] = {b0.x, b0.y, b0.z, b0.w, b1.x, b1.y, b1.z, b1.w, b2.x, b2.y};
#pragma unroll
    for (int d = 0; d < 10; ++d) acc[d] = fmaf(p, vf[d], acc[d]);
  }

  pl[w][lane] = l;
#pragma unroll
  for (int d = 0; d < 10; ++d) pa[w][lane][d] = acc[d];
  __syncthreads();

  if (w == 0) {
    float L = pl[0][lane] + pl[1][lane] + pl[2][lane] + pl[3][lane];
    float a[10];
#pragma unroll
    for (int d = 0; d < 10; ++d)
      a[d] = pa[0][lane][d] + pa[1][lane][d] + pa[2][lane][d] + pa[3][lane][d];
    const float rl = 1.0f / L;
    float* ap = out_att + ((size_t)(bh >> 3) * 1024 + n) * DKV + (bh & 7) * HKK;
#pragma unroll
    for (int dd = 0; dd < 5; ++dd)
      *(float2*)&ap[2 * dd] = make_float2(a[2 * dd] * rl, a[2 * dd + 1] * rl);
    float* qo = qrl + ((size_t)bh * 1024 + n) * 12;
#pragma unroll
    for (int d = 0; d < 10; ++d) qo[d] = qr[d];
    qo[10] = rl;
    qo[11] = 0.f;
  }
}

// ---------------- attn B: dist. 2048 blocks x 256 thr ----------------
// block = (bh, 64-q-row tile); wave = 256-col strip; lane = 4 cols -> b128 stores.
// q+rl via wave-uniform s_load of 48B qrl records (sK$-resident); K strip in VGPRs.
__global__ __launch_bounds__(256) void attn_dist(
    const float* __restrict__ Kdm, const float* __restrict__ qrl,
    float* __restrict__ out_dist) {
  const int t = threadIdx.x;
  const int w = __builtin_amdgcn_readfirstlane(t >> 6);
  const int lane = t & 63;
  const int bid = blockIdx.x;
  const int qt = bid & 15;
  const int bh = bid >> 4;

  const int kb = w * 256 + lane * 4;
  const float4* kp4 = (const float4*)(Kdm + (size_t)bh * 10240);
  float kA[10], kB[10], kC[10], kD[10];
#pragma unroll
  for (int dp = 0; dp < 5; ++dp) {
    float4 va = kp4[dp * 512 + (kb >> 1)];      // cols kb, kb+1
    float4 vb = kp4[dp * 512 + (kb >> 1) + 1];  // cols kb+2, kb+3
    kA[2 * dp] = va.x; kA[2 * dp + 1] = va.y;
    kB[2 * dp] = va.z; kB[2 * dp + 1] = va.w;
    kC[2 * dp] = vb.x; kC[2 * dp + 1] = vb.y;
    kD[2 * dp] = vb.z; kD[2 * dp + 1] = vb.w;
  }

  const float* qbase = qrl + ((size_t)bh * 1024 + qt * 64) * 12;
  float* drow = out_dist + ((size_t)bh * 1024 + qt * 64) * 1024 + kb;
#pragma unroll 2
  for (int qq = 0; qq < 64; ++qq) {
    const float* qp = qbase + qq * 12;  // wave-uniform -> s_load
    float4 qa = *(const float4*)qp;
    float4 qb = *(const float4*)(qp + 4);
    float4 qc = *(const float4*)(qp + 8);  // {q8, q9, rl, pad}
    float qv[10] = {qa.x, qa.y, qa.z, qa.w, qb.x, qb.y, qb.z, qb.w, qc.x, qc.y};
    const float rlq = qc.z;
    float4 o;
    o.x = __expf(dot10(qv, kA)) * rlq;
    o.y = __expf(dot10(qv, kB)) * rlq;
    o.z = __expf(dot10(qv, kC)) * rlq;
    o.w = __expf(dot10(qv, kD)) * rlq;
    *(float4*)&drow[(size_t)qq * 1024] = o;
  }
}

extern "C" void kernel_launch(void* const* d_in, const int* in_sizes, int n_in,
                              void* d_out, int out_size, void* d_ws, size_t ws_size,
                              hipStream_t stream) {
  (void)in_sizes; (void)n_in; (void)out_size; (void)ws_size;
  const float* x = (const float*)d_in[0];
  const float* y = (const float*)d_in[1];
  // d_in[2] = attn_mask (dead arg in the reference forward)
  const float* Wq = (const float*)d_in[3];
  const float* Wk = (const float*)d_in[4];
  const float* Wv = (const float*)d_in[5];

  float* out = (float*)d_out;
  float* att_out = out;
  float* dist_out = out + (size_t)BB * NXX * DKV;

  float* ws = (float*)d_ws;
  float* Pq  = ws;                         // 4 * NP
  float* PKd = ws + 4 * NP;                // 2 * NP
  float* PKr = ws + 6 * NP;                // 2 * NR2
  float* F   = ws + 8 * NP + 2 * NR2;      // [Qhm NP][Kdm NP][KVr NR2]
  float* Qhm = F;
  float* Kdm = F + NP;
  float* KVr = F + 2 * NP;
  float* qrl = F + 2 * NP + NR2;           // 131072 * 12 floats

  proj_q<<<1024, 256, 0, stream>>>(x, Wq, Pq);
  proj_kv<<<512, 512, 0, stream>>>(y, Wk, Wv, PKd, PKr);
  reduce_k<<<2048, 256, 0, stream>>>(ws, F);
  attn_lv<<<BB * NHH * 16, 256, 0, stream>>>(Qhm, KVr, att_out, qrl);
  attn_dist<<<BB * NHH * 16, 256, 0, stream>>>(Kdm, qrl, dist_out);
}